// Round 4
// baseline (1627.970 us; speedup 1.0000x reference)
//
#include <hip/hip_runtime.h>
#include <cmath>

#define Bsz 64
#define Tt  512
#define Dd  768
#define Wn  255
#define Hh  8
#define DHd 96
#define NROWS (Bsz*Wn)   // 16320

typedef _Float16 half_t;
typedef _Float16 f16x8 __attribute__((ext_vector_type(8)));
typedef _Float16 f16x4 __attribute__((ext_vector_type(4)));
typedef float f32x4 __attribute__((ext_vector_type(4)));

// ---- split-fp16 weights as concatenated-K B' panels: [N][3K] = [Bh | Bh | Bl]
// A' = [Ah | Al | Ah] handled by per-tile source mapping. scales: W x64, act x16,
// epilogue descale 1/1024. ~40.5 MiB static device memory.
#define OFF_QKV 0            // 2304 x 2304
#define OFF_WO  5308416      //  768 x 2304
#define OFF_W1  7077888      // 3072 x 2304
#define OFF_W2  14155776     // 4 chunks x [768 x 2304]  (K split 768 each)
#define W2_CSTR 1769472
#define SLOTH 25165824       // halves per 48 MiB workspace slot (q16->k16->v16)
__device__ __align__(16) half_t g_w16[21233664];

__device__ __forceinline__ void gload16(const half_t* g, half_t* l) {
    __builtin_amdgcn_global_load_lds((const __attribute__((address_space(1))) void*)g,
                                     (__attribute__((address_space(3))) void*)l, 16, 0, 0);
}

template<int N> __device__ __forceinline__ void waitv() {
    if constexpr (N == 0) asm volatile("s_waitcnt vmcnt(0)" ::: "memory");
    else if constexpr (N == 1) asm volatile("s_waitcnt vmcnt(1)" ::: "memory");
    else if constexpr (N == 2) asm volatile("s_waitcnt vmcnt(2)" ::: "memory");
    else if constexpr (N == 4) asm volatile("s_waitcnt vmcnt(4)" ::: "memory");
}

// ---------------- gather: first-subtoken index + feature copy ----------------

__global__ void k_init_fi(int* fi) {
    int i = blockIdx.x * 256 + threadIdx.x;
    if (i < Bsz * Wn) fi[i] = 0x7fffffff;
}

__global__ void k_scan(const int* __restrict__ wid, int* __restrict__ fi) {
    int i = blockIdx.x * 256 + threadIdx.x;   // over B*T
    if (i >= Bsz * Tt) return;
    int b = i / Tt, t = i % Tt;
    int w = wid[i];
    if (w >= 0 && w < Wn) atomicMin(&fi[b * Wn + w], t);
}

__global__ void k_bcat(const float* __restrict__ bq, const float* __restrict__ bk,
                       const float* __restrict__ bv, float* __restrict__ o) {
    int i = blockIdx.x * 256 + threadIdx.x;
    if (i < 768) o[i] = bq[i];
    else if (i < 1536) o[i] = bk[i - 768];
    else if (i < 2304) o[i] = bv[i - 1536];
}

// gather directly into interleaved fp16 hi/lo records (row = 1536 halves: hi[768]|lo[768])
__global__ void k_gather(const float4* __restrict__ ob, const int* __restrict__ fi,
                         half_t* __restrict__ f16) {
    int i = blockIdx.x * 256 + threadIdx.x;   // over NROWS*192
    if (i >= NROWS * 192) return;
    int r = i / 192, c = i % 192;
    int b = r / Wn;
    int idx = fi[r];
    if (idx == 0x7fffffff) idx = 0;           // argmax(all-False) == 0
    float4 v = ob[((size_t)b * Tt + idx) * 192 + c];
    float a0 = v.x * 16.f, a1 = v.y * 16.f, a2 = v.z * 16.f, a3 = v.w * 16.f;
    half_t h0 = (half_t)a0, h1 = (half_t)a1, h2 = (half_t)a2, h3 = (half_t)a3;
    f16x4 hv = {h0, h1, h2, h3};
    f16x4 lv = {(half_t)(a0 - (float)h0), (half_t)(a1 - (float)h1),
                (half_t)(a2 - (float)h2), (half_t)(a3 - (float)h3)};
    size_t off = (size_t)r * 1536 + c * 4;
    *(f16x4*)&f16[off] = hv;
    *(f16x4*)&f16[off + 768] = lv;
}

// ---- weight transpose+split: W[K,N] -> B'[n][3*Kseg] = [hi|hi|lo], chunked by Kseg

__global__ void k_wsplit(const float* __restrict__ Wm, int K, int N,
                         size_t obase, int Kseg, size_t cstride) {
    __shared__ float sm[32][33];
    const int tx = threadIdx.x, ty = threadIdx.y;
    const int n0 = blockIdx.x * 32, k0 = blockIdx.y * 32;
    #pragma unroll
    for (int r = 0; r < 4; ++r)
        sm[ty + r * 8][tx] = Wm[(size_t)(k0 + ty + r * 8) * N + n0 + tx];
    __syncthreads();
    #pragma unroll
    for (int r = 0; r < 4; ++r) {
        float v = 64.f * sm[tx][ty + r * 8];
        half_t hi = (half_t)v;
        half_t lo = (half_t)(v - (float)hi);
        int k = k0 + tx;
        int n = n0 + ty + r * 8;
        int c = k / Kseg, kk = k - c * Kseg;
        half_t* o = g_w16 + obase + (size_t)c * cstride + (size_t)n * (3 * Kseg) + kk;
        o[0] = hi; o[Kseg] = hi; o[2 * Kseg] = lo;
    }
}

// ---------------- 128x192 split-fp16 MFMA GEMM, counted-vmcnt, 2 blocks/CU ---
// Same schedule as round 3 (verified), with the K-loop made fully compile-time:
// template<K>, #pragma unroll over NT=3K/64, per-thread base pointers computed
// once (B: 3 chunk bases; A: 2 planes x 2 chunks), segment select and buffer
// parity constant-folded. Stage = gload16(base + t*64, lds_const) -> backend
// folds into the instruction's imm offset; near-zero per-tile address VALU.
// Waits: mid-tile vmcnt(4) (drains this tile's B2), boundary vmcnt(1)
// (drains next B0,B1,A0,A1; leaves next B2). Never 0 in steady state.
// MODE 5: fused QKV -> q16/k16/v16 head-major [bh][256][hi96|lo96]
// MODE 1: fp32 out + interleaved fp16-pair residual (O-proj); AMODE 1: ctx head-major A
// MODE 2: relu -> fp16 hi/lo plane pair x16 (FFN1 N-chunk)
// MODE 3: fp32 out = acc + bias + res (in-place over res OK: same-thread RMW)
// MODE 4: fp32 out += acc (no bias) -- FFN2 K-chunk accumulation

template<int MODE, int AMODE, int K>
__global__ __launch_bounds__(512, 4) void k_gemm128(
    const half_t* __restrict__ Ah, const half_t* __restrict__ Al, int lda,
    size_t boff, const float* __restrict__ bias,
    const void* res, void* out0, void* out1,
    int M, int N) {
    constexpr int NT = (3 * K) >> 6;
    constexpr int Kp3 = 3 * K;
    __shared__ half_t sm[2][20480];
    const int tid = threadIdx.x;
    const int w = tid >> 6, l = tid & 63;
    const int wm = w >> 2, wn = w & 3;
    const int fr = l & 15, q4 = l >> 4;
    const int ck0 = (q4 * 8) ^ ((fr & 7) << 3);   // swizzled col (halves), ks=0
    const int ck1 = ck0 ^ 32;                     // ks=1

    // XCD-locality swizzle (nwg % 8 == 0 for all our grids)
    int lin = blockIdx.y * gridDim.x + blockIdx.x;
    int nwg = gridDim.x * gridDim.y;
    int wg = (lin & 7) * (nwg >> 3) + (lin >> 3);
    int by = wg / gridDim.x, bx = wg - by * gridDim.x;
    const int row0 = by * 128, col0 = bx * 192;

    // ---- per-thread staging constants (computed once) ----
    const int sj = (tid & 7) ^ ((tid >> 3) & 7);
    const int sj8 = sj * 8;
    const int lwave = (tid >> 6) * 512;           // LDS dst lane-wave offset (halves)
    const int rB = (wn * 16 + fr) * 64;           // LDS read row base within chunk

    const half_t* bB0; const half_t* bB1; const half_t* bB2;
    {
        const half_t* Bs = g_w16 + boff;
        int g0 = col0 + (tid >> 3);
        bB0 = Bs + (size_t)g0 * Kp3 + sj8;
        bB1 = Bs + (size_t)(g0 + 64) * Kp3 + sj8;
        bB2 = Bs + (size_t)(g0 + 128) * Kp3 + sj8;
    }
    const half_t* aH0; const half_t* aH1; const half_t* aL0; const half_t* aL1;
    int lam0 = 0, lam1 = 0;
    {
        int gr0 = row0 + (tid >> 3);       if (gr0 > M - 1) gr0 = M - 1;
        int gr1 = row0 + 64 + (tid >> 3);  if (gr1 > M - 1) gr1 = M - 1;
        if (AMODE == 0) {
            aH0 = Ah + (size_t)gr0 * lda + sj8;
            aH1 = Ah + (size_t)gr1 * lda + sj8;
            aL0 = Al + (size_t)gr0 * lda + sj8;
            aL1 = Al + (size_t)gr1 * lda + sj8;
        } else {
            int b0_ = gr0 / 255, wl0 = gr0 - b0_ * 255;
            int b1_ = gr1 / 255, wl1 = gr1 - b1_ * 255;
            lam0 = b0_ * 393216 + wl0 * 192;
            lam1 = b1_ * 393216 + wl1 * 192;
            aH0 = aH1 = aL0 = aL1 = Ah;   // unused paths
        }
    }

    f32x4 acc[4][3];
    #pragma unroll
    for (int m = 0; m < 4; ++m)
        #pragma unroll
        for (int j = 0; j < 3; ++j) acc[m][j] = (f32x4){0.f, 0.f, 0.f, 0.f};

    // prologue: stage tile 0 in steady-state issue order [B0,B1,A0,A1,B2]
    {
        half_t* d0 = &sm[0][0];
        gload16(bB0, d0 + 8192 + lwave);
        gload16(bB1, d0 + 8192 + 4096 + lwave);
        if (AMODE == 0) {
            gload16(aH0, d0 + lwave);
            gload16(aH1, d0 + 4096 + lwave);
        } else {
            int k = sj8;
            int h = k / 96, d = k - h * 96;
            gload16(Ah + lam0 + h * 49152 + d, d0 + lwave);
            gload16(Ah + lam1 + h * 49152 + d, d0 + 4096 + lwave);
        }
        gload16(bB2, d0 + 16384 + lwave);
    }
    waitv<1>();
    __builtin_amdgcn_s_barrier();
    asm volatile("" ::: "memory");

    #pragma unroll
    for (int t = 0; t < NT; ++t) {
        const int p = t & 1;
        half_t* nxt = &sm[p ^ 1][0];
        const half_t* pA = &sm[p][wm * 4096];
        const half_t* pB = &sm[p][8192];
        const int tn = t + 1;
        const bool pf = tn < NT;
        const int segn = (tn * 64 >= 2 * K) ? 2 : ((tn * 64 >= K) ? 1 : 0);
        const int kkn = tn * 64 - segn * K;

        // ---- sub0: B chunks 0,1 + all A frags; stage next {B0,B1,A0,A1} ----
        f16x8 b0[2], b1[2], a0[4], a1[4];
        #pragma unroll
        for (int j = 0; j < 2; ++j) {
            const half_t* p_ = &pB[j * 4096 + rB];
            b0[j] = *(const f16x8*)&p_[ck0];
            b1[j] = *(const f16x8*)&p_[ck1];
        }
        #pragma unroll
        for (int m = 0; m < 4; ++m) {
            a0[m] = *(const f16x8*)&pA[m * 1024 + fr * 64 + ck0];
            a1[m] = *(const f16x8*)&pA[m * 1024 + fr * 64 + ck1];
        }
        if (pf) {
            gload16(bB0 + tn * 64, nxt + 8192 + lwave);
            gload16(bB1 + tn * 64, nxt + 8192 + 4096 + lwave);
            if (AMODE == 0) {
                const half_t* s0 = (segn == 1) ? aL0 : aH0;
                const half_t* s1 = (segn == 1) ? aL1 : aH1;
                gload16(s0 + kkn, nxt + lwave);
                gload16(s1 + kkn, nxt + 4096 + lwave);
            } else {
                const int soff = (segn == 1) ? 96 : 0;
                int k = kkn + sj8;
                int h = k / 96, d = k - h * 96;
                int off = h * 49152 + d + soff;
                gload16(Ah + lam0 + off, nxt + lwave);
                gload16(Ah + lam1 + off, nxt + 4096 + lwave);
            }
        }
        __builtin_amdgcn_s_setprio(1);
        #pragma unroll
        for (int m = 0; m < 4; ++m)
            #pragma unroll
            for (int j = 0; j < 2; ++j) {
                acc[m][j] = __builtin_amdgcn_mfma_f32_16x16x32_f16(a0[m], b0[j], acc[m][j], 0, 0, 0);
                acc[m][j] = __builtin_amdgcn_mfma_f32_16x16x32_f16(a1[m], b1[j], acc[m][j], 0, 0, 0);
            }
        __builtin_amdgcn_s_setprio(0);
        if (pf) waitv<4>();
        else    waitv<0>();
        __builtin_amdgcn_s_barrier();
        asm volatile("" ::: "memory");

        // ---- sub1: B chunk 2 (reuses A frags); stage next {B2} ----
        f16x8 c0, c1;
        {
            const half_t* p_ = &pB[2 * 4096 + rB];
            c0 = *(const f16x8*)&p_[ck0];
            c1 = *(const f16x8*)&p_[ck1];
        }
        if (pf) gload16(bB2 + tn * 64, nxt + 16384 + lwave);
        __builtin_amdgcn_s_setprio(1);
        #pragma unroll
        for (int m = 0; m < 4; ++m) {
            acc[m][2] = __builtin_amdgcn_mfma_f32_16x16x32_f16(a0[m], c0, acc[m][2], 0, 0, 0);
            acc[m][2] = __builtin_amdgcn_mfma_f32_16x16x32_f16(a1[m], c1, acc[m][2], 0, 0, 0);
        }
        __builtin_amdgcn_s_setprio(0);
        if (pf) {
            waitv<1>();
            __builtin_amdgcn_s_barrier();
            asm volatile("" ::: "memory");
        }
    }

    // ---- epilogue ----
    const float dsc = 1.0f / 1024.0f;
    #pragma unroll
    for (int m = 0; m < 4; ++m) {
        #pragma unroll
        for (int r = 0; r < 4; ++r) {
            const int row = row0 + wm * 64 + m * 16 + q4 * 4 + r;
            if (row >= M) continue;
            #pragma unroll
            for (int j = 0; j < 3; ++j) {
                const int col = col0 + j * 64 + wn * 16 + fr;
                float vv = acc[m][j][r] * dsc;
                if (MODE != 4) vv += bias[col];
                if (MODE == 5) {
                    int part = col / 768, cc = col - part * 768;
                    int h = cc / 96, d = cc - h * 96;
                    int b = row / 255, wl = row - b * 255;
                    float t16 = vv * 16.f;
                    half_t hi = (half_t)t16;
                    half_t lo = (half_t)(t16 - (float)hi);
                    half_t* dstp = (half_t*)out0 + (size_t)part * SLOTH;
                    size_t o = ((size_t)(b * 8 + h) * 256 + wl) * 192 + d;
                    dstp[o] = hi; dstp[o + 96] = lo;
                } else if (MODE == 1) {
                    const half_t* rp = (const half_t*)res;
                    vv += ((float)rp[(size_t)row * 1536 + col] +
                           (float)rp[(size_t)row * 1536 + 768 + col]) * 0.0625f;
                    ((float*)out0)[(size_t)row * N + col] = vv;
                } else if (MODE == 2) {
                    vv = fmaxf(vv, 0.f);
                    float t16 = vv * 16.f;
                    half_t hi = (half_t)t16;
                    ((half_t*)out0)[(size_t)row * N + col] = hi;
                    ((half_t*)out1)[(size_t)row * N + col] = (half_t)(t16 - (float)hi);
                } else if (MODE == 3) {
                    vv += ((const float*)res)[(size_t)row * N + col];
                    ((float*)out0)[(size_t)row * N + col] = vv;
                } else {   // MODE 4: accumulate (same-thread RMW, stream-serialized)
                    float* op = (float*)out0 + (size_t)row * N + col;
                    *op += vv;
                }
            }
        }
    }
}

// ---------------- flash MFMA attention, split-fp16, one block per (b,h) ------
// (unchanged from previous verified version)

__global__ __launch_bounds__(256, 2) void k_attn2(half_t* __restrict__ qc,
                                                  const half_t* __restrict__ kk16,
                                                  const half_t* __restrict__ vv16) {
    __shared__ half_t sK[64][200];
    __shared__ half_t sVT[192][72];
    __shared__ float  sP[4][16][68];
    const int tid = threadIdx.x;
    const int w = tid >> 6, l = tid & 63;
    const int lr = l & 15, lc = l >> 4;
    const size_t base = (size_t)blockIdx.x * 49152;
    const float ssc = 0.10206207261596575f / 256.0f;

    for (int pass = 0; pass < 2; ++pass) {
        f32x4 O[2][6];
        float mrow[2][4], lrow[2][4];
        #pragma unroll
        for (int qs = 0; qs < 2; ++qs) {
            #pragma unroll
            for (int dn = 0; dn < 6; ++dn) O[qs][dn] = (f32x4){0.f, 0.f, 0.f, 0.f};
            #pragma unroll
            for (int r = 0; r < 4; ++r) { mrow[qs][r] = -3e38f; lrow[qs][r] = 0.f; }
        }
        for (int kt = 0; kt < 4; ++kt) {
            __syncthreads();
            #pragma unroll
            for (int c = 0; c < 6; ++c) {
                int ch = w + c * 4;
                *(f16x8*)&sK[l][ch * 8] =
                    *(const f16x8*)(kk16 + base + (size_t)(kt * 64 + l) * 192 + ch * 8);
            }
            #pragma unroll
            for (int c = 0; c < 6; ++c) {
                int ch = w + c * 4;
                f16x8 vv = *(const f16x8*)(vv16 + base + (size_t)(kt * 64 + l) * 192 + ch * 8);
                #pragma unroll
                for (int j = 0; j < 8; ++j) sVT[ch * 8 + j][l] = vv[j];
            }
            __syncthreads();
            #pragma unroll
            for (int qs = 0; qs < 2; ++qs) {
                const int qrow0 = (pass * 2 + qs) * 64 + w * 16;
                f16x8 qf0[3], qf1[3];
                #pragma unroll
                for (int s = 0; s < 3; ++s) {
                    qf0[s] = *(const f16x8*)(qc + base + (size_t)(qrow0 + lr) * 192 + s * 32 + lc * 8);
                    qf1[s] = *(const f16x8*)(qc + base + (size_t)(qrow0 + lr) * 192 + 96 + s * 32 + lc * 8);
                }
                f32x4 sacc[4];
                #pragma unroll
                for (int nt = 0; nt < 4; ++nt) sacc[nt] = (f32x4){0.f, 0.f, 0.f, 0.f};
                #pragma unroll
                for (int s = 0; s < 3; ++s)
                    #pragma unroll
                    for (int nt = 0; nt < 4; ++nt) {
                        f16x8 kh = *(const f16x8*)&sK[nt * 16 + lr][s * 32 + lc * 8];
                        f16x8 klo = *(const f16x8*)&sK[nt * 16 + lr][96 + s * 32 + lc * 8];
                        sacc[nt] = __builtin_amdgcn_mfma_f32_16x16x32_f16(qf0[s], kh, sacc[nt], 0, 0, 0);
                        sacc[nt] = __builtin_amdgcn_mfma_f32_16x16x32_f16(qf0[s], klo, sacc[nt], 0, 0, 0);
                        sacc[nt] = __builtin_amdgcn_mfma_f32_16x16x32_f16(qf1[s], kh, sacc[nt], 0, 0, 0);
                    }
                float sv[4][4], mx[4] = {-3e38f, -3e38f, -3e38f, -3e38f};
                #pragma unroll
                for (int nt = 0; nt < 4; ++nt) {
                    int key = kt * 64 + nt * 16 + lr;
                    #pragma unroll
                    for (int r = 0; r < 4; ++r) {
                        float s_ = sacc[nt][r] * ssc;
                        if (key >= 255) s_ = -3e38f;
                        sv[nt][r] = s_;
                        mx[r] = fmaxf(mx[r], s_);
                    }
                }
                #pragma unroll
                for (int r = 0; r < 4; ++r) {
                    mx[r] = fmaxf(mx[r], __shfl_xor(mx[r], 1));
                    mx[r] = fmaxf(mx[r], __shfl_xor(mx[r], 2));
                    mx[r] = fmaxf(mx[r], __shfl_xor(mx[r], 4));
                    mx[r] = fmaxf(mx[r], __shfl_xor(mx[r], 8));
                }
                float alpha[4], rsum[4];
                #pragma unroll
                for (int r = 0; r < 4; ++r) {
                    float mn = fmaxf(mrow[qs][r], mx[r]);
                    alpha[r] = __expf(mrow[qs][r] - mn);
                    mrow[qs][r] = mn;
                    rsum[r] = 0.f;
                }
                float pv[4][4];
                #pragma unroll
                for (int nt = 0; nt < 4; ++nt)
                    #pragma unroll
                    for (int r = 0; r < 4; ++r) {
                        float p = __expf(sv[nt][r] - mrow[qs][r]);
                        pv[nt][r] = p;
                        rsum[r] += p;
                    }
                #pragma unroll
                for (int r = 0; r < 4; ++r) {
                    rsum[r] += __shfl_xor(rsum[r], 1);
                    rsum[r] += __shfl_xor(rsum[r], 2);
                    rsum[r] += __shfl_xor(rsum[r], 4);
                    rsum[r] += __shfl_xor(rsum[r], 8);
                    lrow[qs][r] = lrow[qs][r] * alpha[r] + rsum[r];
                }
                #pragma unroll
                for (int dn = 0; dn < 6; ++dn)
                    #pragma unroll
                    for (int r = 0; r < 4; ++r) O[qs][dn][r] *= alpha[r];
                #pragma unroll
                for (int nt = 0; nt < 4; ++nt)
                    #pragma unroll
                    for (int r = 0; r < 4; ++r)
                        sP[w][lc * 4 + r][nt * 16 + lr] = pv[nt][r];
                #pragma unroll
                for (int ks = 0; ks < 2; ++ks) {
                    const float* pp = &sP[w][lr][ks * 32 + lc * 8];
                    f16x8 ph, pl;
                    #pragma unroll
                    for (int j = 0; j < 8; ++j) {
                        float p = pp[j];
                        half_t h_ = (half_t)p;
                        ph[j] = h_;
                        pl[j] = (half_t)(p - (float)h_);
                    }
                    #pragma unroll
                    for (int dn = 0; dn < 6; ++dn) {
                        f16x8 vh = *(const f16x8*)&sVT[dn * 16 + lr][ks * 32 + lc * 8];
                        f16x8 vl = *(const f16x8*)&sVT[96 + dn * 16 + lr][ks * 32 + lc * 8];
                        O[qs][dn] = __builtin_amdgcn_mfma_f32_16x16x32_f16(ph, vh, O[qs][dn], 0, 0, 0);
                        O[qs][dn] = __builtin_amdgcn_mfma_f32_16x16x32_f16(ph, vl, O[qs][dn], 0, 0, 0);
                        O[qs][dn] = __builtin_amdgcn_mfma_f32_16x16x32_f16(pl, vh, O[qs][dn], 0, 0, 0);
                    }
                }
            }
        }
        #pragma unroll
        for (int qs = 0; qs < 2; ++qs) {
            const int qrow0 = (pass * 2 + qs) * 64 + w * 16;
            #pragma unroll
            for (int r = 0; r < 4; ++r) {
                int qrow = qrow0 + lc * 4 + r;
                if (qrow >= Wn) continue;
                float inv = 1.0f / lrow[qs][r];
                #pragma unroll
                for (int dn = 0; dn < 6; ++dn) {
                    float val = O[qs][dn][r] * inv;
                    half_t hi = (half_t)val;
                    half_t lo = (half_t)(val - (float)hi);
                    size_t o = base + (size_t)qrow * 192 + dn * 16 + lr;
                    qc[o] = hi;
                    qc[o + 96] = lo;
                }
            }
        }
    }
}

// ---------------- row LayerNorm (optional fused fp16-pair split output) -----

template<int SPLIT>
__global__ __launch_bounds__(256) void k_ln(const float* __restrict__ X, const float* __restrict__ g,
                                            const float* __restrict__ bt, float* __restrict__ Y,
                                            half_t* __restrict__ Y16) {
    const int r = blockIdx.x, tid = threadIdx.x;
    __shared__ float red[256];
    const float* x = X + (size_t)r * Dd;
    float x0 = x[tid], x1 = x[tid + 256], x2 = x[tid + 512];
    red[tid] = x0 + x1 + x2; __syncthreads();
    for (int s = 128; s > 0; s >>= 1) { if (tid < s) red[tid] += red[tid + s]; __syncthreads(); }
    float mean = red[0] * (1.0f / 768.0f);
    __syncthreads();
    float d0 = x0 - mean, d1 = x1 - mean, d2 = x2 - mean;
    red[tid] = d0 * d0 + d1 * d1 + d2 * d2; __syncthreads();
    for (int s = 128; s > 0; s >>= 1) { if (tid < s) red[tid] += red[tid + s]; __syncthreads(); }
    float rs = rsqrtf(red[0] * (1.0f / 768.0f) + 1e-5f);
    float* y = Y + (size_t)r * Dd;
    float y0 = d0 * rs * g[tid]       + bt[tid];
    float y1 = d1 * rs * g[tid + 256] + bt[tid + 256];
    float y2 = d2 * rs * g[tid + 512] + bt[tid + 512];
    y[tid] = y0; y[tid + 256] = y1; y[tid + 512] = y2;
    if (SPLIT) {
        half_t* h = Y16 + (size_t)r * 1536;
        float t0 = y0 * 16.f, t1 = y1 * 16.f, t2 = y2 * 16.f;
        half_t h0 = (half_t)t0, h1 = (half_t)t1, h2 = (half_t)t2;
        h[tid] = h0; h[tid + 256] = h1; h[tid + 512] = h2;
        h[768 + tid] = (half_t)(t0 - (float)h0);
        h[768 + tid + 256] = (half_t)(t1 - (float)h1);
        h[768 + tid + 512] = (half_t)(t2 - (float)h2);
    }
}

// ---------------- final LN + 2-class linear + softmax + argmax --------------

__global__ __launch_bounds__(256) void k_final(const float* __restrict__ X, const float* __restrict__ g,
                                               const float* __restrict__ bt, const float* __restrict__ lw,
                                               const float* __restrict__ lb, float* __restrict__ out) {
    const int r = blockIdx.x, tid = threadIdx.x;
    __shared__ float red[256];
    const float* x = X + (size_t)r * Dd;
    float x0 = x[tid], x1 = x[tid + 256], x2 = x[tid + 512];
    red[tid] = x0 + x1 + x2; __syncthreads();
    for (int s = 128; s > 0; s >>= 1) { if (tid < s) red[tid] += red[tid + s]; __syncthreads(); }
    float mean = red[0] * (1.0f / 768.0f);
    __syncthreads();
    float d0 = x0 - mean, d1 = x1 - mean, d2 = x2 - mean;
    red[tid] = d0 * d0 + d1 * d1 + d2 * d2; __syncthreads();
    for (int s = 128; s > 0; s >>= 1) { if (tid < s) red[tid] += red[tid + s]; __syncthreads(); }
    float rs = rsqrtf(red[0] * (1.0f / 768.0f) + 1e-5f);
    __syncthreads();
    float n0 = d0 * rs * g[tid]       + bt[tid];
    float n1 = d1 * rs * g[tid + 256] + bt[tid + 256];
    float n2 = d2 * rs * g[tid + 512] + bt[tid + 512];
    float l0 = n0 * lw[2 * tid]     + n1 * lw[2 * (tid + 256)]     + n2 * lw[2 * (tid + 512)];
    float l1 = n0 * lw[2 * tid + 1] + n1 * lw[2 * (tid + 256) + 1] + n2 * lw[2 * (tid + 512) + 1];
    red[tid] = l0; __syncthreads();
    for (int s = 128; s > 0; s >>= 1) { if (tid < s) red[tid] += red[tid + s]; __syncthreads(); }
    l0 = red[0]; __syncthreads();
    red[tid] = l1; __syncthreads();
    for (int s = 128; s > 0; s >>= 1) { if (tid < s) red[tid] += red[tid + s]; __syncthreads(); }
    l1 = red[0];
    if (tid == 0) {
        l0 += lb[0]; l1 += lb[1];
        float m = fmaxf(l0, l1);
        float e0 = expf(l0 - m), e1 = expf(l1 - m);
        float inv = 1.0f / (e0 + e1);
        out[2 * r] = e0 * inv;
        out[2 * r + 1] = e1 * inv;
        out[2 * NROWS + r] = (l1 > l0) ? 1.0f : 0.0f;
    }
}

// ---------------- launch --------------------------------------------------

extern "C" void kernel_launch(void* const* d_in, const int* in_sizes, int n_in,
                              void* d_out, int out_size, void* d_ws, size_t ws_size,
                              hipStream_t stream) {
    const float* ob  = (const float*)d_in[0];
    const int*   wid = (const int*)d_in[1];
    const float* Wq  = (const float*)d_in[2];  const float* bq  = (const float*)d_in[3];
    const float* Wk  = (const float*)d_in[4];  const float* bk  = (const float*)d_in[5];
    const float* Wv  = (const float*)d_in[6];  const float* bv  = (const float*)d_in[7];
    const float* Wo  = (const float*)d_in[8];  const float* bo  = (const float*)d_in[9];
    const float* g1  = (const float*)d_in[10]; const float* b1  = (const float*)d_in[11];
    const float* W1f = (const float*)d_in[12]; const float* b1f = (const float*)d_in[13];
    const float* W2f = (const float*)d_in[14]; const float* b2f = (const float*)d_in[15];
    const float* g2  = (const float*)d_in[16]; const float* b2  = (const float*)d_in[17];
    const float* ng  = (const float*)d_in[18]; const float* nb  = (const float*)d_in[19];
    const float* lw  = (const float*)d_in[20]; const float* lb  = (const float*)d_in[21];
    float* out = (float*)d_out;

    char* ws = (char*)d_ws;
    const size_t MB = 1u << 20;
    const size_t SLOT = 48 * MB;
    int* fi = (int*)ws;
    float* bcat = (float*)(ws + 262144);
    char* S1 = ws + MB;
    char* S2 = S1 + SLOT;
    char* S3 = S2 + SLOT;
    char* S4 = S3 + SLOT;                      // total 193 MiB (proven OK)

    half_t* feat16 = (half_t*)S1;              // interleaved hi|lo, row = 1536 halves
    half_t* q16    = (half_t*)S2;              // [bh][256][192] -> ctx16 in-place
    half_t* k16    = (half_t*)S3;
    half_t* v16    = (half_t*)S4;
    float*  t1     = (float*)S3;               // Wo out (k16 consumed)
    float*  xbuf   = (float*)S4;               // LN1 out; FFN2 accumulates in-place
    half_t* x16    = (half_t*)S2;              // LN1 split out (ctx consumed by Wo)
    half_t* ffh_h  = (half_t*)S1;              // per-N-chunk hidden hi [row][768]
    half_t* ffh_l  = (half_t*)S3;              // per-N-chunk hidden lo [row][768]
    float*  x2     = (float*)S2;               // LN2 out (x16 consumed)

    // weight prep -> concat-K B' panels [N][3K] = [hi|hi|lo]
    k_wsplit<<<dim3(24, 24), dim3(32, 8), 0, stream>>>(Wq, 768, 768, OFF_QKV,                   768, 0);
    k_wsplit<<<dim3(24, 24), dim3(32, 8), 0, stream>>>(Wk, 768, 768, OFF_QKV + 768ul * 2304,    768, 0);
    k_wsplit<<<dim3(24, 24), dim3(32, 8), 0, stream>>>(Wv, 768, 768, OFF_QKV + 1536ul * 2304,   768, 0);
    k_wsplit<<<dim3(24, 24), dim3(32, 8), 0, stream>>>(Wo, 768, 768, OFF_WO,                    768, 0);
    k_wsplit<<<dim3(96, 24), dim3(32, 8), 0, stream>>>(W1f, 768, 3072, OFF_W1,                  768, 0);
    k_wsplit<<<dim3(24, 96), dim3(32, 8), 0, stream>>>(W2f, 3072, 768, OFF_W2,                  768, W2_CSTR);
    k_bcat<<<9, 256, 0, stream>>>(bq, bk, bv, bcat);

    k_init_fi<<<(Bsz * Wn + 255) / 256, 256, 0, stream>>>(fi);
    k_scan<<<(Bsz * Tt) / 256, 256, 0, stream>>>(wid, fi);
    k_gather<<<(NROWS * 192 + 255) / 256, 256, 0, stream>>>((const float4*)ob, fi, feat16);

    // fused QKV: M=16320 N=2304 K=768, 12x128 = 1536 blocks = 3 rounds of 512
    k_gemm128<5, 0, 768><<<dim3(12, 128), 512, 0, stream>>>(
        feat16, feat16 + 768, 1536, OFF_QKV, bcat, nullptr, q16, nullptr, NROWS, 2304);

    k_attn2<<<Bsz * Hh, 256, 0, stream>>>(q16, k16, v16);     // ctx overwrites q16

    // t1 = feat + ctx@Wo + bo ; 4x128 = 512 blocks = 1 round ; x = LN1(t1)
    k_gemm128<1, 1, 768><<<dim3(4, 128), 512, 0, stream>>>(
        q16, q16 + 96, 0, OFF_WO, bo, feat16, t1, nullptr, NROWS, 768);
    k_ln<1><<<NROWS, 256, 0, stream>>>(t1, g1, b1, xbuf, x16);

    // FFN in 4 N-chunks of 768: FFN1 and FFN2 each 512 blocks = 1 round/chunk;
    // FFN2 accumulates into xbuf in-place (chunk0 adds bias+residual).
    for (int c = 0; c < 4; ++c) {
        k_gemm128<2, 0, 768><<<dim3(4, 128), 512, 0, stream>>>(
            x16, x16 + 768, 1536, OFF_W1 + (size_t)c * 768 * 2304, b1f + c * 768,
            nullptr, ffh_h, ffh_l, NROWS, 768);
        if (c == 0)
            k_gemm128<3, 0, 768><<<dim3(4, 128), 512, 0, stream>>>(
                ffh_h, ffh_l, 768, OFF_W2, b2f, xbuf, xbuf, nullptr, NROWS, 768);
        else
            k_gemm128<4, 0, 768><<<dim3(4, 128), 512, 0, stream>>>(
                ffh_h, ffh_l, 768, OFF_W2 + (size_t)c * W2_CSTR, b2f,
                nullptr, xbuf, nullptr, NROWS, 768);
    }

    k_ln<0><<<NROWS, 256, 0, stream>>>(xbuf, g2, b2, x2, nullptr);
    k_final<<<NROWS, 256, 0, stream>>>(x2, ng, nb, lw, lb, out);
}

// Round 5
// 1062.928 us; speedup vs baseline: 1.5316x; 1.5316x over previous
//
#include <hip/hip_runtime.h>
#include <cmath>

#define Bsz 64
#define Tt  512
#define Dd  768
#define Wn  255
#define Hh  8
#define DHd 96
#define NROWS (Bsz*Wn)   // 16320

typedef _Float16 half_t;
typedef _Float16 f16x8 __attribute__((ext_vector_type(8)));
typedef _Float16 f16x4 __attribute__((ext_vector_type(4)));
typedef float f32x4 __attribute__((ext_vector_type(4)));

// ---- split-fp16 weights as concatenated-K B' panels: [N][3K] = [Bh | Bh | Bl]
// A' = [Ah | Al | Ah] handled by per-tile source mapping. scales: W x64, act x16,
// epilogue descale 1/1024. ~40.5 MiB static device memory.
#define OFF_QKV 0            // 2304 x 2304
#define OFF_WO  5308416      //  768 x 2304
#define OFF_W1  7077888      // 3072 x 2304
#define OFF_W2  14155776     // 2 chunks x [768 x 4608]  (K split 1536 each)
#define W2_CSTR 3538944
#define SLOTH 25165824       // halves per 48 MiB workspace slot (q16->k16->v16)
__device__ __align__(16) half_t g_w16[21233664];

__device__ __forceinline__ void gload16(const half_t* g, half_t* l) {
    __builtin_amdgcn_global_load_lds((const __attribute__((address_space(1))) void*)g,
                                     (__attribute__((address_space(3))) void*)l, 16, 0, 0);
}

template<int N> __device__ __forceinline__ void waitv() {
    if constexpr (N == 0) asm volatile("s_waitcnt vmcnt(0)" ::: "memory");
    else if constexpr (N == 1) asm volatile("s_waitcnt vmcnt(1)" ::: "memory");
    else if constexpr (N == 2) asm volatile("s_waitcnt vmcnt(2)" ::: "memory");
    else if constexpr (N == 4) asm volatile("s_waitcnt vmcnt(4)" ::: "memory");
}

// ---------------- gather: first-subtoken index + feature copy ----------------

__global__ void k_init_fi(int* fi) {
    int i = blockIdx.x * 256 + threadIdx.x;
    if (i < Bsz * Wn) fi[i] = 0x7fffffff;
}

__global__ void k_scan(const int* __restrict__ wid, int* __restrict__ fi) {
    int i = blockIdx.x * 256 + threadIdx.x;   // over B*T
    if (i >= Bsz * Tt) return;
    int b = i / Tt, t = i % Tt;
    int w = wid[i];
    if (w >= 0 && w < Wn) atomicMin(&fi[b * Wn + w], t);
}

__global__ void k_bcat(const float* __restrict__ bq, const float* __restrict__ bk,
                       const float* __restrict__ bv, float* __restrict__ o) {
    int i = blockIdx.x * 256 + threadIdx.x;
    if (i < 768) o[i] = bq[i];
    else if (i < 1536) o[i] = bk[i - 768];
    else if (i < 2304) o[i] = bv[i - 1536];
}

// gather directly into interleaved fp16 hi/lo records (row = 1536 halves: hi[768]|lo[768])
__global__ void k_gather(const float4* __restrict__ ob, const int* __restrict__ fi,
                         half_t* __restrict__ f16) {
    int i = blockIdx.x * 256 + threadIdx.x;   // over NROWS*192
    if (i >= NROWS * 192) return;
    int r = i / 192, c = i % 192;
    int b = r / Wn;
    int idx = fi[r];
    if (idx == 0x7fffffff) idx = 0;           // argmax(all-False) == 0
    float4 v = ob[((size_t)b * Tt + idx) * 192 + c];
    float a0 = v.x * 16.f, a1 = v.y * 16.f, a2 = v.z * 16.f, a3 = v.w * 16.f;
    half_t h0 = (half_t)a0, h1 = (half_t)a1, h2 = (half_t)a2, h3 = (half_t)a3;
    f16x4 hv = {h0, h1, h2, h3};
    f16x4 lv = {(half_t)(a0 - (float)h0), (half_t)(a1 - (float)h1),
                (half_t)(a2 - (float)h2), (half_t)(a3 - (float)h3)};
    size_t off = (size_t)r * 1536 + c * 4;
    *(f16x4*)&f16[off] = hv;
    *(f16x4*)&f16[off + 768] = lv;
}

// ---- weight transpose+split: W[K,N] -> B'[n][3*Kseg] = [hi|hi|lo], chunked by Kseg

__global__ void k_wsplit(const float* __restrict__ Wm, int K, int N,
                         size_t obase, int Kseg, size_t cstride) {
    __shared__ float sm[32][33];
    const int tx = threadIdx.x, ty = threadIdx.y;
    const int n0 = blockIdx.x * 32, k0 = blockIdx.y * 32;
    #pragma unroll
    for (int r = 0; r < 4; ++r)
        sm[ty + r * 8][tx] = Wm[(size_t)(k0 + ty + r * 8) * N + n0 + tx];
    __syncthreads();
    #pragma unroll
    for (int r = 0; r < 4; ++r) {
        float v = 64.f * sm[tx][ty + r * 8];
        half_t hi = (half_t)v;
        half_t lo = (half_t)(v - (float)hi);
        int k = k0 + tx;
        int n = n0 + ty + r * 8;
        int c = k / Kseg, kk = k - c * Kseg;
        half_t* o = g_w16 + obase + (size_t)c * cstride + (size_t)n * (3 * Kseg) + kk;
        o[0] = hi; o[Kseg] = hi; o[2 * Kseg] = lo;
    }
}

// ---------------- 128x192 split-fp16 MFMA GEMM, counted-vmcnt, 2 blocks/CU ---
// Round-3 verified schedule (rolled loop), with per-thread global base pointers
// hoisted out of the loop (round-4 idea) but NO full unroll (round-4's full
// unroll caused scratch spills: +180MB sym. FETCH/WRITE). #pragma unroll 2
// only folds the dbuf parity. Stage = gload16(base + t*64, lds_const); LSR
// strength-reduces t*64 into an induction variable -> near-zero address VALU.
// Waits: mid-tile vmcnt(4) (drains this tile's B2), boundary vmcnt(1)
// (drains next B0,B1,A0,A1; leaves next B2). Never 0 in steady state.
// MODE 5: fused QKV -> q16/k16/v16 head-major [bh][256][hi96|lo96]
// MODE 1: fp32 out + interleaved fp16-pair residual (O-proj); AMODE 1: ctx head-major A
// MODE 2: relu -> fp16 hi/lo plane pair x16 (FFN1 N-chunk)
// MODE 3: fp32 out = acc + bias + res (in-place over res OK: same-thread RMW)
// MODE 4: fp32 out += acc (no bias) -- FFN2 K-chunk accumulation

template<int MODE, int AMODE, int K>
__global__ __launch_bounds__(512, 4) void k_gemm128(
    const half_t* __restrict__ Ah, const half_t* __restrict__ Al, int lda,
    size_t boff, const float* __restrict__ bias,
    const void* res, void* out0, void* out1,
    int M, int N) {
    constexpr int NT = (3 * K) >> 6;
    constexpr int Kp3 = 3 * K;
    __shared__ half_t sm[2][20480];
    const int tid = threadIdx.x;
    const int w = tid >> 6, l = tid & 63;
    const int wm = w >> 2, wn = w & 3;
    const int fr = l & 15, q4 = l >> 4;
    const int ck0 = (q4 * 8) ^ ((fr & 7) << 3);   // swizzled col (halves), ks=0
    const int ck1 = ck0 ^ 32;                     // ks=1

    // XCD-locality swizzle (nwg % 8 == 0 for all our grids)
    int lin = blockIdx.y * gridDim.x + blockIdx.x;
    int nwg = gridDim.x * gridDim.y;
    int wg = (lin & 7) * (nwg >> 3) + (lin >> 3);
    int by = wg / gridDim.x, bx = wg - by * gridDim.x;
    const int row0 = by * 128, col0 = bx * 192;

    // ---- per-thread staging constants (computed once) ----
    const int sj8 = ((tid & 7) ^ ((tid >> 3) & 7)) * 8;
    const int lwave = (tid >> 6) * 512;           // LDS dst lane-wave offset (halves)
    const int rB = (wn * 16 + fr) * 64;           // LDS read row base within chunk

    const half_t* bB0; const half_t* bB1; const half_t* bB2;
    {
        const half_t* Bs = g_w16 + boff;
        int g0 = col0 + (tid >> 3);
        bB0 = Bs + (size_t)g0 * Kp3 + sj8;
        bB1 = bB0 + (size_t)64 * Kp3;
        bB2 = bB0 + (size_t)128 * Kp3;
    }
    const half_t* aH0; const half_t* aH1; const half_t* aL0; const half_t* aL1;
    int lam0 = 0, lam1 = 0;
    {
        int gr0 = row0 + (tid >> 3);       if (gr0 > M - 1) gr0 = M - 1;
        int gr1 = row0 + 64 + (tid >> 3);  if (gr1 > M - 1) gr1 = M - 1;
        if (AMODE == 0) {
            aH0 = Ah + (size_t)gr0 * lda + sj8;
            aH1 = Ah + (size_t)gr1 * lda + sj8;
            aL0 = Al + (size_t)gr0 * lda + sj8;
            aL1 = Al + (size_t)gr1 * lda + sj8;
        } else {
            int b0_ = gr0 / 255, wl0 = gr0 - b0_ * 255;
            int b1_ = gr1 / 255, wl1 = gr1 - b1_ * 255;
            lam0 = b0_ * 393216 + wl0 * 192;
            lam1 = b1_ * 393216 + wl1 * 192;
            aH0 = aH1 = aL0 = aL1 = Ah;   // unused paths
        }
    }

    f32x4 acc[4][3];
    #pragma unroll
    for (int m = 0; m < 4; ++m)
        #pragma unroll
        for (int j = 0; j < 3; ++j) acc[m][j] = (f32x4){0.f, 0.f, 0.f, 0.f};

    // prologue: stage tile 0 in steady-state issue order [B0,B1,A0,A1,B2]
    {
        half_t* d0 = &sm[0][0];
        gload16(bB0, d0 + 8192 + lwave);
        gload16(bB1, d0 + 12288 + lwave);
        if (AMODE == 0) {
            gload16(aH0, d0 + lwave);
            gload16(aH1, d0 + 4096 + lwave);
        } else {
            int h = sj8 / 96, d = sj8 - h * 96;
            gload16(Ah + lam0 + h * 49152 + d, d0 + lwave);
            gload16(Ah + lam1 + h * 49152 + d, d0 + 4096 + lwave);
        }
        gload16(bB2, d0 + 16384 + lwave);
    }
    waitv<1>();
    __builtin_amdgcn_s_barrier();
    asm volatile("" ::: "memory");

    #pragma unroll 2
    for (int t = 0; t < NT; ++t) {
        const int p = t & 1;
        half_t* nxt = &sm[p ^ 1][0];
        const half_t* pA = &sm[p][wm * 4096];
        const half_t* pB = &sm[p][8192];
        const int tn = t + 1;
        const bool pf = tn < NT;
        const int segn = (tn * 64 >= 2 * K) ? 2 : ((tn * 64 >= K) ? 1 : 0);
        const int kkn = tn * 64 - segn * K;

        // ---- sub0: B chunks 0,1 + all A frags; stage next {B0,B1,A0,A1} ----
        f16x8 b0[2], b1[2], a0[4], a1[4];
        #pragma unroll
        for (int j = 0; j < 2; ++j) {
            const half_t* p_ = &pB[j * 4096 + rB];
            b0[j] = *(const f16x8*)&p_[ck0];
            b1[j] = *(const f16x8*)&p_[ck1];
        }
        #pragma unroll
        for (int m = 0; m < 4; ++m) {
            a0[m] = *(const f16x8*)&pA[m * 1024 + fr * 64 + ck0];
            a1[m] = *(const f16x8*)&pA[m * 1024 + fr * 64 + ck1];
        }
        if (pf) {
            gload16(bB0 + tn * 64, nxt + 8192 + lwave);
            gload16(bB1 + tn * 64, nxt + 12288 + lwave);
            if (AMODE == 0) {
                const half_t* s0 = (segn == 1) ? aL0 : aH0;
                const half_t* s1 = (segn == 1) ? aL1 : aH1;
                gload16(s0 + kkn, nxt + lwave);
                gload16(s1 + kkn, nxt + 4096 + lwave);
            } else {
                const int soff = (segn == 1) ? 96 : 0;
                int k = kkn + sj8;
                int h = k / 96, d = k - h * 96;
                int off = h * 49152 + d + soff;
                gload16(Ah + lam0 + off, nxt + lwave);
                gload16(Ah + lam1 + off, nxt + 4096 + lwave);
            }
        }
        __builtin_amdgcn_s_setprio(1);
        #pragma unroll
        for (int m = 0; m < 4; ++m)
            #pragma unroll
            for (int j = 0; j < 2; ++j) {
                acc[m][j] = __builtin_amdgcn_mfma_f32_16x16x32_f16(a0[m], b0[j], acc[m][j], 0, 0, 0);
                acc[m][j] = __builtin_amdgcn_mfma_f32_16x16x32_f16(a1[m], b1[j], acc[m][j], 0, 0, 0);
            }
        __builtin_amdgcn_s_setprio(0);
        if (pf) waitv<4>();
        else    waitv<0>();
        __builtin_amdgcn_s_barrier();
        asm volatile("" ::: "memory");

        // ---- sub1: B chunk 2 (reuses A frags); stage next {B2} ----
        f16x8 c0, c1;
        {
            const half_t* p_ = &pB[2 * 4096 + rB];
            c0 = *(const f16x8*)&p_[ck0];
            c1 = *(const f16x8*)&p_[ck1];
        }
        if (pf) gload16(bB2 + tn * 64, nxt + 16384 + lwave);
        __builtin_amdgcn_s_setprio(1);
        #pragma unroll
        for (int m = 0; m < 4; ++m) {
            acc[m][2] = __builtin_amdgcn_mfma_f32_16x16x32_f16(a0[m], c0, acc[m][2], 0, 0, 0);
            acc[m][2] = __builtin_amdgcn_mfma_f32_16x16x32_f16(a1[m], c1, acc[m][2], 0, 0, 0);
        }
        __builtin_amdgcn_s_setprio(0);
        if (pf) {
            waitv<1>();
            __builtin_amdgcn_s_barrier();
            asm volatile("" ::: "memory");
        }
    }

    // ---- epilogue ----
    const float dsc = 1.0f / 1024.0f;
    #pragma unroll
    for (int m = 0; m < 4; ++m) {
        #pragma unroll
        for (int r = 0; r < 4; ++r) {
            const int row = row0 + wm * 64 + m * 16 + q4 * 4 + r;
            if (row >= M) continue;
            #pragma unroll
            for (int j = 0; j < 3; ++j) {
                const int col = col0 + j * 64 + wn * 16 + fr;
                float vv = acc[m][j][r] * dsc;
                if (MODE != 4) vv += bias[col];
                if (MODE == 5) {
                    int part = col / 768, cc = col - part * 768;
                    int h = cc / 96, d = cc - h * 96;
                    int b = row / 255, wl = row - b * 255;
                    float t16 = vv * 16.f;
                    half_t hi = (half_t)t16;
                    half_t lo = (half_t)(t16 - (float)hi);
                    half_t* dstp = (half_t*)out0 + (size_t)part * SLOTH;
                    size_t o = ((size_t)(b * 8 + h) * 256 + wl) * 192 + d;
                    dstp[o] = hi; dstp[o + 96] = lo;
                } else if (MODE == 1) {
                    const half_t* rp = (const half_t*)res;
                    vv += ((float)rp[(size_t)row * 1536 + col] +
                           (float)rp[(size_t)row * 1536 + 768 + col]) * 0.0625f;
                    ((float*)out0)[(size_t)row * N + col] = vv;
                } else if (MODE == 2) {
                    vv = fmaxf(vv, 0.f);
                    float t16 = vv * 16.f;
                    half_t hi = (half_t)t16;
                    ((half_t*)out0)[(size_t)row * N + col] = hi;
                    ((half_t*)out1)[(size_t)row * N + col] = (half_t)(t16 - (float)hi);
                } else if (MODE == 3) {
                    vv += ((const float*)res)[(size_t)row * N + col];
                    ((float*)out0)[(size_t)row * N + col] = vv;
                } else {   // MODE 4: accumulate (same-thread RMW, stream-serialized)
                    float* op = (float*)out0 + (size_t)row * N + col;
                    *op += vv;
                }
            }
        }
    }
}

// ---------------- flash MFMA attention, split-fp16, one block per (b,h) ------
// (unchanged from previous verified version)

__global__ __launch_bounds__(256, 2) void k_attn2(half_t* __restrict__ qc,
                                                  const half_t* __restrict__ kk16,
                                                  const half_t* __restrict__ vv16) {
    __shared__ half_t sK[64][200];
    __shared__ half_t sVT[192][72];
    __shared__ float  sP[4][16][68];
    const int tid = threadIdx.x;
    const int w = tid >> 6, l = tid & 63;
    const int lr = l & 15, lc = l >> 4;
    const size_t base = (size_t)blockIdx.x * 49152;
    const float ssc = 0.10206207261596575f / 256.0f;

    for (int pass = 0; pass < 2; ++pass) {
        f32x4 O[2][6];
        float mrow[2][4], lrow[2][4];
        #pragma unroll
        for (int qs = 0; qs < 2; ++qs) {
            #pragma unroll
            for (int dn = 0; dn < 6; ++dn) O[qs][dn] = (f32x4){0.f, 0.f, 0.f, 0.f};
            #pragma unroll
            for (int r = 0; r < 4; ++r) { mrow[qs][r] = -3e38f; lrow[qs][r] = 0.f; }
        }
        for (int kt = 0; kt < 4; ++kt) {
            __syncthreads();
            #pragma unroll
            for (int c = 0; c < 6; ++c) {
                int ch = w + c * 4;
                *(f16x8*)&sK[l][ch * 8] =
                    *(const f16x8*)(kk16 + base + (size_t)(kt * 64 + l) * 192 + ch * 8);
            }
            #pragma unroll
            for (int c = 0; c < 6; ++c) {
                int ch = w + c * 4;
                f16x8 vv = *(const f16x8*)(vv16 + base + (size_t)(kt * 64 + l) * 192 + ch * 8);
                #pragma unroll
                for (int j = 0; j < 8; ++j) sVT[ch * 8 + j][l] = vv[j];
            }
            __syncthreads();
            #pragma unroll
            for (int qs = 0; qs < 2; ++qs) {
                const int qrow0 = (pass * 2 + qs) * 64 + w * 16;
                f16x8 qf0[3], qf1[3];
                #pragma unroll
                for (int s = 0; s < 3; ++s) {
                    qf0[s] = *(const f16x8*)(qc + base + (size_t)(qrow0 + lr) * 192 + s * 32 + lc * 8);
                    qf1[s] = *(const f16x8*)(qc + base + (size_t)(qrow0 + lr) * 192 + 96 + s * 32 + lc * 8);
                }
                f32x4 sacc[4];
                #pragma unroll
                for (int nt = 0; nt < 4; ++nt) sacc[nt] = (f32x4){0.f, 0.f, 0.f, 0.f};
                #pragma unroll
                for (int s = 0; s < 3; ++s)
                    #pragma unroll
                    for (int nt = 0; nt < 4; ++nt) {
                        f16x8 kh = *(const f16x8*)&sK[nt * 16 + lr][s * 32 + lc * 8];
                        f16x8 klo = *(const f16x8*)&sK[nt * 16 + lr][96 + s * 32 + lc * 8];
                        sacc[nt] = __builtin_amdgcn_mfma_f32_16x16x32_f16(qf0[s], kh, sacc[nt], 0, 0, 0);
                        sacc[nt] = __builtin_amdgcn_mfma_f32_16x16x32_f16(qf0[s], klo, sacc[nt], 0, 0, 0);
                        sacc[nt] = __builtin_amdgcn_mfma_f32_16x16x32_f16(qf1[s], kh, sacc[nt], 0, 0, 0);
                    }
                float sv[4][4], mx[4] = {-3e38f, -3e38f, -3e38f, -3e38f};
                #pragma unroll
                for (int nt = 0; nt < 4; ++nt) {
                    int key = kt * 64 + nt * 16 + lr;
                    #pragma unroll
                    for (int r = 0; r < 4; ++r) {
                        float s_ = sacc[nt][r] * ssc;
                        if (key >= 255) s_ = -3e38f;
                        sv[nt][r] = s_;
                        mx[r] = fmaxf(mx[r], s_);
                    }
                }
                #pragma unroll
                for (int r = 0; r < 4; ++r) {
                    mx[r] = fmaxf(mx[r], __shfl_xor(mx[r], 1));
                    mx[r] = fmaxf(mx[r], __shfl_xor(mx[r], 2));
                    mx[r] = fmaxf(mx[r], __shfl_xor(mx[r], 4));
                    mx[r] = fmaxf(mx[r], __shfl_xor(mx[r], 8));
                }
                float alpha[4], rsum[4];
                #pragma unroll
                for (int r = 0; r < 4; ++r) {
                    float mn = fmaxf(mrow[qs][r], mx[r]);
                    alpha[r] = __expf(mrow[qs][r] - mn);
                    mrow[qs][r] = mn;
                    rsum[r] = 0.f;
                }
                float pv[4][4];
                #pragma unroll
                for (int nt = 0; nt < 4; ++nt)
                    #pragma unroll
                    for (int r = 0; r < 4; ++r) {
                        float p = __expf(sv[nt][r] - mrow[qs][r]);
                        pv[nt][r] = p;
                        rsum[r] += p;
                    }
                #pragma unroll
                for (int r = 0; r < 4; ++r) {
                    rsum[r] += __shfl_xor(rsum[r], 1);
                    rsum[r] += __shfl_xor(rsum[r], 2);
                    rsum[r] += __shfl_xor(rsum[r], 4);
                    rsum[r] += __shfl_xor(rsum[r], 8);
                    lrow[qs][r] = lrow[qs][r] * alpha[r] + rsum[r];
                }
                #pragma unroll
                for (int dn = 0; dn < 6; ++dn)
                    #pragma unroll
                    for (int r = 0; r < 4; ++r) O[qs][dn][r] *= alpha[r];
                #pragma unroll
                for (int nt = 0; nt < 4; ++nt)
                    #pragma unroll
                    for (int r = 0; r < 4; ++r)
                        sP[w][lc * 4 + r][nt * 16 + lr] = pv[nt][r];
                #pragma unroll
                for (int ks = 0; ks < 2; ++ks) {
                    const float* pp = &sP[w][lr][ks * 32 + lc * 8];
                    f16x8 ph, pl;
                    #pragma unroll
                    for (int j = 0; j < 8; ++j) {
                        float p = pp[j];
                        half_t h_ = (half_t)p;
                        ph[j] = h_;
                        pl[j] = (half_t)(p - (float)h_);
                    }
                    #pragma unroll
                    for (int dn = 0; dn < 6; ++dn) {
                        f16x8 vh = *(const f16x8*)&sVT[dn * 16 + lr][ks * 32 + lc * 8];
                        f16x8 vl = *(const f16x8*)&sVT[96 + dn * 16 + lr][ks * 32 + lc * 8];
                        O[qs][dn] = __builtin_amdgcn_mfma_f32_16x16x32_f16(ph, vh, O[qs][dn], 0, 0, 0);
                        O[qs][dn] = __builtin_amdgcn_mfma_f32_16x16x32_f16(ph, vl, O[qs][dn], 0, 0, 0);
                        O[qs][dn] = __builtin_amdgcn_mfma_f32_16x16x32_f16(pl, vh, O[qs][dn], 0, 0, 0);
                    }
                }
            }
        }
        #pragma unroll
        for (int qs = 0; qs < 2; ++qs) {
            const int qrow0 = (pass * 2 + qs) * 64 + w * 16;
            #pragma unroll
            for (int r = 0; r < 4; ++r) {
                int qrow = qrow0 + lc * 4 + r;
                if (qrow >= Wn) continue;
                float inv = 1.0f / lrow[qs][r];
                #pragma unroll
                for (int dn = 0; dn < 6; ++dn) {
                    float val = O[qs][dn][r] * inv;
                    half_t hi = (half_t)val;
                    half_t lo = (half_t)(val - (float)hi);
                    size_t o = base + (size_t)qrow * 192 + dn * 16 + lr;
                    qc[o] = hi;
                    qc[o + 96] = lo;
                }
            }
        }
    }
}

// ---------------- row LayerNorm (optional fused fp16-pair split output) -----

template<int SPLIT>
__global__ __launch_bounds__(256) void k_ln(const float* __restrict__ X, const float* __restrict__ g,
                                            const float* __restrict__ bt, float* __restrict__ Y,
                                            half_t* __restrict__ Y16) {
    const int r = blockIdx.x, tid = threadIdx.x;
    __shared__ float red[256];
    const float* x = X + (size_t)r * Dd;
    float x0 = x[tid], x1 = x[tid + 256], x2 = x[tid + 512];
    red[tid] = x0 + x1 + x2; __syncthreads();
    for (int s = 128; s > 0; s >>= 1) { if (tid < s) red[tid] += red[tid + s]; __syncthreads(); }
    float mean = red[0] * (1.0f / 768.0f);
    __syncthreads();
    float d0 = x0 - mean, d1 = x1 - mean, d2 = x2 - mean;
    red[tid] = d0 * d0 + d1 * d1 + d2 * d2; __syncthreads();
    for (int s = 128; s > 0; s >>= 1) { if (tid < s) red[tid] += red[tid + s]; __syncthreads(); }
    float rs = rsqrtf(red[0] * (1.0f / 768.0f) + 1e-5f);
    float* y = Y + (size_t)r * Dd;
    float y0 = d0 * rs * g[tid]       + bt[tid];
    float y1 = d1 * rs * g[tid + 256] + bt[tid + 256];
    float y2 = d2 * rs * g[tid + 512] + bt[tid + 512];
    y[tid] = y0; y[tid + 256] = y1; y[tid + 512] = y2;
    if (SPLIT) {
        half_t* h = Y16 + (size_t)r * 1536;
        float t0 = y0 * 16.f, t1 = y1 * 16.f, t2 = y2 * 16.f;
        half_t h0 = (half_t)t0, h1 = (half_t)t1, h2 = (half_t)t2;
        h[tid] = h0; h[tid + 256] = h1; h[tid + 512] = h2;
        h[768 + tid] = (half_t)(t0 - (float)h0);
        h[768 + tid + 256] = (half_t)(t1 - (float)h1);
        h[768 + tid + 512] = (half_t)(t2 - (float)h2);
    }
}

// ---------------- final LN + 2-class linear + softmax + argmax --------------

__global__ __launch_bounds__(256) void k_final(const float* __restrict__ X, const float* __restrict__ g,
                                               const float* __restrict__ bt, const float* __restrict__ lw,
                                               const float* __restrict__ lb, float* __restrict__ out) {
    const int r = blockIdx.x, tid = threadIdx.x;
    __shared__ float red[256];
    const float* x = X + (size_t)r * Dd;
    float x0 = x[tid], x1 = x[tid + 256], x2 = x[tid + 512];
    red[tid] = x0 + x1 + x2; __syncthreads();
    for (int s = 128; s > 0; s >>= 1) { if (tid < s) red[tid] += red[tid + s]; __syncthreads(); }
    float mean = red[0] * (1.0f / 768.0f);
    __syncthreads();
    float d0 = x0 - mean, d1 = x1 - mean, d2 = x2 - mean;
    red[tid] = d0 * d0 + d1 * d1 + d2 * d2; __syncthreads();
    for (int s = 128; s > 0; s >>= 1) { if (tid < s) red[tid] += red[tid + s]; __syncthreads(); }
    float rs = rsqrtf(red[0] * (1.0f / 768.0f) + 1e-5f);
    __syncthreads();
    float n0 = d0 * rs * g[tid]       + bt[tid];
    float n1 = d1 * rs * g[tid + 256] + bt[tid + 256];
    float n2 = d2 * rs * g[tid + 512] + bt[tid + 512];
    float l0 = n0 * lw[2 * tid]     + n1 * lw[2 * (tid + 256)]     + n2 * lw[2 * (tid + 512)];
    float l1 = n0 * lw[2 * tid + 1] + n1 * lw[2 * (tid + 256) + 1] + n2 * lw[2 * (tid + 512) + 1];
    red[tid] = l0; __syncthreads();
    for (int s = 128; s > 0; s >>= 1) { if (tid < s) red[tid] += red[tid + s]; __syncthreads(); }
    l0 = red[0]; __syncthreads();
    red[tid] = l1; __syncthreads();
    for (int s = 128; s > 0; s >>= 1) { if (tid < s) red[tid] += red[tid + s]; __syncthreads(); }
    l1 = red[0];
    if (tid == 0) {
        l0 += lb[0]; l1 += lb[1];
        float m = fmaxf(l0, l1);
        float e0 = expf(l0 - m), e1 = expf(l1 - m);
        float inv = 1.0f / (e0 + e1);
        out[2 * r] = e0 * inv;
        out[2 * r + 1] = e1 * inv;
        out[2 * NROWS + r] = (l1 > l0) ? 1.0f : 0.0f;
    }
}

// ---------------- launch --------------------------------------------------

extern "C" void kernel_launch(void* const* d_in, const int* in_sizes, int n_in,
                              void* d_out, int out_size, void* d_ws, size_t ws_size,
                              hipStream_t stream) {
    const float* ob  = (const float*)d_in[0];
    const int*   wid = (const int*)d_in[1];
    const float* Wq  = (const float*)d_in[2];  const float* bq  = (const float*)d_in[3];
    const float* Wk  = (const float*)d_in[4];  const float* bk  = (const float*)d_in[5];
    const float* Wv  = (const float*)d_in[6];  const float* bv  = (const float*)d_in[7];
    const float* Wo  = (const float*)d_in[8];  const float* bo  = (const float*)d_in[9];
    const float* g1  = (const float*)d_in[10]; const float* b1  = (const float*)d_in[11];
    const float* W1f = (const float*)d_in[12]; const float* b1f = (const float*)d_in[13];
    const float* W2f = (const float*)d_in[14]; const float* b2f = (const float*)d_in[15];
    const float* g2  = (const float*)d_in[16]; const float* b2  = (const float*)d_in[17];
    const float* ng  = (const float*)d_in[18]; const float* nb  = (const float*)d_in[19];
    const float* lw  = (const float*)d_in[20]; const float* lb  = (const float*)d_in[21];
    float* out = (float*)d_out;

    char* ws = (char*)d_ws;
    const size_t MB = 1u << 20;
    const size_t SLOT = 48 * MB;
    int* fi = (int*)ws;
    float* bcat = (float*)(ws + 262144);
    char* S1 = ws + MB;
    char* S2 = S1 + SLOT;
    char* S3 = S2 + SLOT;
    char* S4 = S3 + SLOT;                      // total 193 MiB (proven OK)

    half_t* feat16 = (half_t*)S1;              // interleaved hi|lo, row = 1536 halves
    half_t* q16    = (half_t*)S2;              // [bh][256][192] -> ctx16 in-place
    half_t* k16    = (half_t*)S3;
    half_t* v16    = (half_t*)S4;
    float*  t1     = (float*)S3;               // Wo out (k16 consumed)
    float*  xbuf   = (float*)S4;               // LN1 out; FFN2 accumulates in-place
    half_t* x16    = (half_t*)S2;              // LN1 split out (ctx consumed by Wo)
    half_t* ffh_h  = (half_t*)S1;              // per-N-chunk hidden hi [row][1536] (50.1MB<=48MiB slot)
    half_t* ffh_l  = (half_t*)S3;              // per-N-chunk hidden lo [row][1536]
    float*  x2     = (float*)S2;               // LN2 out (x16 consumed)

    // weight prep -> concat-K B' panels [N][3K] = [hi|hi|lo]
    k_wsplit<<<dim3(24, 24), dim3(32, 8), 0, stream>>>(Wq, 768, 768, OFF_QKV,                   768, 0);
    k_wsplit<<<dim3(24, 24), dim3(32, 8), 0, stream>>>(Wk, 768, 768, OFF_QKV + 768ul * 2304,    768, 0);
    k_wsplit<<<dim3(24, 24), dim3(32, 8), 0, stream>>>(Wv, 768, 768, OFF_QKV + 1536ul * 2304,   768, 0);
    k_wsplit<<<dim3(24, 24), dim3(32, 8), 0, stream>>>(Wo, 768, 768, OFF_WO,                    768, 0);
    k_wsplit<<<dim3(96, 24), dim3(32, 8), 0, stream>>>(W1f, 768, 3072, OFF_W1,                  768, 0);
    k_wsplit<<<dim3(24, 96), dim3(32, 8), 0, stream>>>(W2f, 3072, 768, OFF_W2,                 1536, W2_CSTR);
    k_bcat<<<9, 256, 0, stream>>>(bq, bk, bv, bcat);

    k_init_fi<<<(Bsz * Wn + 255) / 256, 256, 0, stream>>>(fi);
    k_scan<<<(Bsz * Tt) / 256, 256, 0, stream>>>(wid, fi);
    k_gather<<<(NROWS * 192 + 255) / 256, 256, 0, stream>>>((const float4*)ob, fi, feat16);

    // fused QKV: M=16320 N=2304 K=768, 12x128 = 1536 blocks = 3 rounds of 512
    k_gemm128<5, 0, 768><<<dim3(12, 128), 512, 0, stream>>>(
        feat16, feat16 + 768, 1536, OFF_QKV, bcat, nullptr, q16, nullptr, NROWS, 2304);

    k_attn2<<<Bsz * Hh, 256, 0, stream>>>(q16, k16, v16);     // ctx overwrites q16

    // t1 = feat + ctx@Wo + bo ; 4x128 = 512 blocks = 1 round ; x = LN1(t1)
    k_gemm128<1, 1, 768><<<dim3(4, 128), 512, 0, stream>>>(
        q16, q16 + 96, 0, OFF_WO, bo, feat16, t1, nullptr, NROWS, 768);
    k_ln<1><<<NROWS, 256, 0, stream>>>(t1, g1, b1, xbuf, x16);

    // FFN in 2 N-chunks of 1536: FFN1 8x128=1024 blocks (2 rounds),
    // FFN2 K=1536/chunk (NT=72), 4x128=512 blocks (1 round);
    // FFN2 accumulates into xbuf in-place (chunk0 adds bias+residual).
    for (int c = 0; c < 2; ++c) {
        k_gemm128<2, 0, 768><<<dim3(8, 128), 512, 0, stream>>>(
            x16, x16 + 768, 1536, OFF_W1 + (size_t)c * 1536 * 2304, b1f + c * 1536,
            nullptr, ffh_h, ffh_l, NROWS, 1536);
        if (c == 0)
            k_gemm128<3, 0, 1536><<<dim3(4, 128), 512, 0, stream>>>(
                ffh_h, ffh_l, 1536, OFF_W2, b2f, xbuf, xbuf, nullptr, NROWS, 768);
        else
            k_gemm128<4, 0, 1536><<<dim3(4, 128), 512, 0, stream>>>(
                ffh_h, ffh_l, 1536, OFF_W2 + (size_t)W2_CSTR, b2f,
                nullptr, xbuf, nullptr, NROWS, 768);
    }

    k_ln<0><<<NROWS, 256, 0, stream>>>(xbuf, g2, b2, x2, nullptr);
    k_final<<<NROWS, 256, 0, stream>>>(x2, ng, nb, lw, lb, out);
}